// Round 1
// baseline (646.360 us; speedup 1.0000x reference)
//
#include <hip/hip_runtime.h>
#include <hip/hip_bf16.h>

typedef __attribute__((ext_vector_type(4))) float  f32x4;
typedef __attribute__((ext_vector_type(8))) short  s16x8;
typedef __attribute__((ext_vector_type(4))) short  s16x4;

constexpr int I_SZ = 2048;
constexpr int O_SZ = 2048;
constexpr int T_SZ = 2048;
constexpr int BM = 128, BN = 128, BK = 32;
constexpr int LDK = 40;            // padded LDS K-stride (bf16 elems) = 80B rows
constexpr int NKT = I_SZ / BK;     // 64 K-steps

__device__ __forceinline__ short f2bf(float f) {
    __hip_bfloat16 h = __float2bfloat16(f);   // RNE; compiler pairs into v_cvt_pk_bf16_f32
    return *reinterpret_cast<short*>(&h);
}

__global__ __launch_bounds__(256) void dal_gemm(
    const float* __restrict__ x,
    const int*   __restrict__ dom_id,
    const float* __restrict__ fcw,
    const float* __restrict__ bw,
    float*       __restrict__ out)
{
    __shared__ short As[2][BM * LDK];   // A tile, [m][k] row-major, padded
    __shared__ short Bs[2][BN * LDK];   // B tile TRANSPOSED: [n][k] row-major, padded

    const int bz = blockIdx.z;
    const int m0 = blockIdx.y * BM;
    const int n0 = blockIdx.x * BN;
    const int dom = dom_id[bz];

    const float* Ag = x + ((size_t)bz * T_SZ + m0) * I_SZ;                    // [m][k]
    const float* Wg = fcw + (size_t)dom * ((size_t)I_SZ * O_SZ) + n0;         // [k][n]

    const int t = threadIdx.x;

    // ---- staging coordinates ----
    // A: 128 rows x 32 cols fp32; thread covers 4 float4 (rows am+32p, cols ac..ac+3)
    const int am = t >> 3;             // 0..31
    const int ac = (t & 7) << 2;       // 0,4,...,28
    // B: 32 k x 128 n fp32; thread covers 4x4 micro-tile (k = bk..bk+3, n = bn..bn+3)
    const int bk = (t >> 5) << 2;      // 0,4,...,28
    const int bn = (t & 31) << 2;      // 0,4,...,124

    // ---- wave / fragment coordinates ----
    const int wv   = t >> 6;
    const int lane = t & 63;
    const int wr   = (wv >> 1) << 6;   // wave row offset: 0 or 64
    const int wc   = (wv & 1)  << 6;   // wave col offset: 0 or 64
    const int hi   = lane >> 4;        // 0..3 -> k-subgroup
    const int lr   = lane & 15;        // A-row / B-col / D-col within 16

    f32x4 acc[4][4] = {};              // 4x4 fragments of 16x16 = 64x64 per wave

    f32x4 ra[4], rb[4];

    auto load_tile = [&](int kb) {
        #pragma unroll
        for (int p = 0; p < 4; ++p)
            ra[p] = *reinterpret_cast<const f32x4*>(Ag + (size_t)(am + 32 * p) * I_SZ + kb + ac);
        #pragma unroll
        for (int r = 0; r < 4; ++r)
            rb[r] = *reinterpret_cast<const f32x4*>(Wg + (size_t)(kb + bk + r) * O_SZ + bn);
    };

    auto store_tile = [&](int buf) {
        #pragma unroll
        for (int p = 0; p < 4; ++p) {
            s16x4 h = { f2bf(ra[p][0]), f2bf(ra[p][1]), f2bf(ra[p][2]), f2bf(ra[p][3]) };
            *reinterpret_cast<s16x4*>(&As[buf][(am + 32 * p) * LDK + ac]) = h;
        }
        #pragma unroll
        for (int i = 0; i < 4; ++i) {  // in-register 4x4 transpose: [k][n] -> [n][k]
            s16x4 h = { f2bf(rb[0][i]), f2bf(rb[1][i]), f2bf(rb[2][i]), f2bf(rb[3][i]) };
            *reinterpret_cast<s16x4*>(&Bs[buf][(bn + i) * LDK + bk]) = h;
        }
    };

    // prologue
    load_tile(0);
    store_tile(0);
    __syncthreads();

    for (int kt = 0; kt < NKT; ++kt) {
        const int cur = kt & 1;

        // issue next tile's global loads early; HBM latency hides under MFMA below
        if (kt + 1 < NKT) load_tile((kt + 1) * BK);

        // fragment loads: split-K-block mapping
        // lane holds k = 4*hi + (j&3) + 16*(j>>2), j = 0..7
        s16x8 af[4], bfr[4];
        #pragma unroll
        for (int im = 0; im < 4; ++im) {
            const short* p = &As[cur][(wr + im * 16 + lr) * LDK + 4 * hi];
            s16x4 lo = *reinterpret_cast<const s16x4*>(p);
            s16x4 hh = *reinterpret_cast<const s16x4*>(p + 16);
            af[im] = __builtin_shufflevector(lo, hh, 0, 1, 2, 3, 4, 5, 6, 7);
        }
        #pragma unroll
        for (int in = 0; in < 4; ++in) {
            const short* p = &Bs[cur][(wc + in * 16 + lr) * LDK + 4 * hi];
            s16x4 lo = *reinterpret_cast<const s16x4*>(p);
            s16x4 hh = *reinterpret_cast<const s16x4*>(p + 16);
            bfr[in] = __builtin_shufflevector(lo, hh, 0, 1, 2, 3, 4, 5, 6, 7);
        }

        #pragma unroll
        for (int im = 0; im < 4; ++im)
            #pragma unroll
            for (int in = 0; in < 4; ++in)
                acc[im][in] = __builtin_amdgcn_mfma_f32_16x16x32_bf16(
                                  af[im], bfr[in], acc[im][in], 0, 0, 0);

        // convert + write next tile (waits on vmcnt automatically)
        if (kt + 1 < NKT) store_tile(cur ^ 1);
        __syncthreads();
    }

    // ---- epilogue: bias + store ----
    float bias[4];
    #pragma unroll
    for (int in = 0; in < 4; ++in)
        bias[in] = bw[dom * O_SZ + n0 + wc + in * 16 + lr];

    const size_t obase = ((size_t)bz * T_SZ + m0) * O_SZ + n0;
    #pragma unroll
    for (int im = 0; im < 4; ++im) {
        #pragma unroll
        for (int r = 0; r < 4; ++r) {
            const int row = wr + im * 16 + hi * 4 + r;   // verified C/D: row=4*(lane>>4)+reg
            float* orow = out + obase + (size_t)row * O_SZ;
            #pragma unroll
            for (int in = 0; in < 4; ++in)
                orow[wc + in * 16 + lr] = acc[im][in][r] + bias[in];  // col = lane&15
        }
    }
}

extern "C" void kernel_launch(void* const* d_in, const int* in_sizes, int n_in,
                              void* d_out, int out_size, void* d_ws, size_t ws_size,
                              hipStream_t stream) {
    const float* x   = (const float*)d_in[0];
    const int*   dom = (const int*)d_in[1];
    const float* fcw = (const float*)d_in[2];
    const float* bw  = (const float*)d_in[3];
    float* out = (float*)d_out;

    const int B = in_sizes[1];  // 16
    dim3 grid(O_SZ / BN, T_SZ / BM, B);
    dal_gemm<<<grid, dim3(256), 0, stream>>>(x, dom, fcw, bw, out);
}

// Round 3
// 581.957 us; speedup vs baseline: 1.1107x; 1.1107x over previous
//
#include <hip/hip_runtime.h>
#include <hip/hip_bf16.h>
#include <stdint.h>

typedef __attribute__((ext_vector_type(4))) float  f32x4;
typedef __attribute__((ext_vector_type(8))) short  s16x8;
typedef __attribute__((ext_vector_type(4))) short  s16x4;

constexpr int I_SZ = 2048;
constexpr int O_SZ = 2048;
constexpr int T_SZ = 2048;
constexpr int B_MAX = 16;

// pre-tiled layout: per (bz, mtile/ntile of 128, ktile of 32): 8KB block =
// 8 subtiles (16 rows each) x 1KB; within a subtile, byte offset l*16 holds
// fragment of lane l: row = l&15, k = 4*(l>>4) + {0..3} and 16 + 4*(l>>4) + {0..3}
constexpr size_t XT_ELEMS = (size_t)B_MAX * T_SZ * I_SZ;         // 67,108,864 shorts
constexpr size_t WT_ELEMS = (size_t)B_MAX * I_SZ * O_SZ;
constexpr size_t WS_NEEDED = (XT_ELEMS + WT_ELEMS) * sizeof(short); // 256 MB

__device__ __forceinline__ short f2bf(float f) {
    __hip_bfloat16 h = __float2bfloat16(f);
    return *reinterpret_cast<short*>(&h);
}

__device__ __forceinline__ void gload_lds16(const void* g, void* l) {
    __builtin_amdgcn_global_load_lds(
        (const __attribute__((address_space(1))) unsigned int*)g,
        (__attribute__((address_space(3))) unsigned int*)l, 16, 0, 0);
}

// ---------------- conversion: x fp32 [B][T][I] -> pre-tiled bf16 ----------------
__global__ __launch_bounds__(256) void convA(const float* __restrict__ x,
                                             short* __restrict__ xt) {
    const int c = blockIdx.x * 256 + threadIdx.x;    // 16B-chunk id
    const int l  = c & 63;
    const int mi = (c >> 6) & 7;
    const int kt = (c >> 9) & 63;
    const int rest = c >> 15;                        // (bz*16 + mt)
    const int mt = rest & 15, bz = rest >> 4;
    const int lr = l & 15, hi = l >> 4;
    const int m = mt * 128 + mi * 16 + lr;
    const float* src = x + ((size_t)(bz * T_SZ + m)) * I_SZ + kt * 32 + 4 * hi;
    f32x4 a = *reinterpret_cast<const f32x4*>(src);
    f32x4 b = *reinterpret_cast<const f32x4*>(src + 16);
    s16x8 h = { f2bf(a[0]), f2bf(a[1]), f2bf(a[2]), f2bf(a[3]),
                f2bf(b[0]), f2bf(b[1]), f2bf(b[2]), f2bf(b[3]) };
    *reinterpret_cast<s16x8*>(xt + (size_t)c * 8) = h;
}

// ------- conversion: W fp32 [dom][I][O] gathered+transposed -> pre-tiled bf16 ----
__global__ __launch_bounds__(256) void convB(const float* __restrict__ fcw,
                                             const int* __restrict__ dom_id,
                                             short* __restrict__ wt) {
    const int c = blockIdx.x * 256 + threadIdx.x;
    const int l  = c & 63;
    const int ni = (c >> 6) & 7;
    const int kt = (c >> 9) & 63;
    const int rest = c >> 15;                        // (bz*16 + nt)
    const int nt = rest & 15, bz = rest >> 4;
    const int lr = l & 15, hi = l >> 4;
    const int n = nt * 128 + ni * 16 + lr;
    const int dom = dom_id[bz];
    const float* src = fcw + (size_t)dom * ((size_t)I_SZ * O_SZ)
                           + (size_t)(kt * 32 + 4 * hi) * O_SZ + n;
    short h[8];
    #pragma unroll
    for (int j = 0; j < 4; ++j) {
        h[j]     = f2bf(src[(size_t)j * O_SZ]);
        h[4 + j] = f2bf(src[(size_t)(16 + j) * O_SZ]);
    }
    *reinterpret_cast<s16x8*>(wt + (size_t)c * 8) =
        *reinterpret_cast<s16x8*>(h);
}

// ---------------- bf16 GEMM, m97 structure, conflict-free fragments --------------
__global__ __launch_bounds__(256) void gemm_bf16(const short* __restrict__ xt,
                                                 const short* __restrict__ wt,
                                                 const float* __restrict__ bw,
                                                 const int*   __restrict__ dom_id,
                                                 float*       __restrict__ out) {
    __shared__ short As[2][4096];   // 8KB per buffer, pre-tiled image
    __shared__ short Bs[2][4096];

    const int bz = blockIdx.z, mt = blockIdx.y, nt = blockIdx.x;
    const short* Abase = xt + (size_t)(bz * 16 + mt) * 64 * 4096;
    const short* Bbase = wt + (size_t)(bz * 16 + nt) * 64 * 4096;

    const int t = threadIdx.x;
    const int wv = t >> 6, l = t & 63;
    const int lr = l & 15, hi = l >> 4;
    const int wr = (wv >> 1) * 4;   // A subtile base (0 or 4)
    const int wc = (wv & 1) * 4;    // B subtile base (0 or 4)

    auto stage = [&](int buf, int kt) {
        const short* Asrc = Abase + (size_t)kt * 4096;
        const short* Bsrc = Bbase + (size_t)kt * 4096;
        #pragma unroll
        for (int i = 0; i < 2; ++i) {
            const int s = wv * 2 + i;
            gload_lds16(Asrc + (s * 64 + l) * 8, &As[buf][s * 512]);
            gload_lds16(Bsrc + (s * 64 + l) * 8, &Bs[buf][s * 512]);
        }
    };

    f32x4 acc[4][4] = {};

    stage(0, 0);
    // RACE FIX (round 2 post-mortem): global_load_lds has no register dest, so
    // the compiler may not drain vmcnt before s_barrier. Explicitly drain so the
    // async LDS writes have landed before any wave crosses the barrier.
    asm volatile("s_waitcnt vmcnt(0)" ::: "memory");
    __syncthreads();

    for (int kt = 0; kt < 64; ++kt) {
        const int cur = kt & 1;
        if (kt + 1 < 64) stage(cur ^ 1, kt + 1);

        s16x8 af[4], bq[4];
        #pragma unroll
        for (int im = 0; im < 4; ++im)
            af[im] = *reinterpret_cast<const s16x8*>(&As[cur][(wr + im) * 512 + l * 8]);
        #pragma unroll
        for (int in = 0; in < 4; ++in)
            bq[in] = *reinterpret_cast<const s16x8*>(&Bs[cur][(wc + in) * 512 + l * 8]);

        #pragma unroll
        for (int im = 0; im < 4; ++im)
            #pragma unroll
            for (int in = 0; in < 4; ++in)
                acc[im][in] = __builtin_amdgcn_mfma_f32_16x16x32_bf16(
                                  af[im], bq[in], acc[im][in], 0, 0, 0);

        // Drain this iteration's prefetch before releasing waves into the next
        // iteration's ds_reads of the freshly staged buffer.
        asm volatile("s_waitcnt vmcnt(0)" ::: "memory");
        __syncthreads();
    }

    const int dom = dom_id[bz];
    float bias[4];
    #pragma unroll
    for (int in = 0; in < 4; ++in)
        bias[in] = bw[dom * O_SZ + nt * 128 + (wc + in) * 16 + lr];

    const size_t obase = ((size_t)bz * T_SZ + mt * 128) * O_SZ + nt * 128;
    #pragma unroll
    for (int im = 0; im < 4; ++im) {
        #pragma unroll
        for (int r = 0; r < 4; ++r) {
            const int row = (wr + im) * 16 + hi * 4 + r;
            float* orow = out + obase + (size_t)row * O_SZ;
            #pragma unroll
            for (int in = 0; in < 4; ++in)
                orow[(wc + in) * 16 + lr] = acc[im][in][r] + bias[in];
        }
    }
}

// =============== fallback (round-1 kernel) if workspace is too small ===============
constexpr int BM = 128, BN = 128, BK = 32;
constexpr int LDK = 40;
constexpr int NKT = I_SZ / BK;

__global__ __launch_bounds__(256) void dal_gemm(
    const float* __restrict__ x, const int* __restrict__ dom_id,
    const float* __restrict__ fcw, const float* __restrict__ bw,
    float* __restrict__ out)
{
    __shared__ short As[2][BM * LDK];
    __shared__ short Bs[2][BN * LDK];
    const int bz = blockIdx.z;
    const int m0 = blockIdx.y * BM, n0 = blockIdx.x * BN;
    const int dom = dom_id[bz];
    const float* Ag = x + ((size_t)bz * T_SZ + m0) * I_SZ;
    const float* Wg = fcw + (size_t)dom * ((size_t)I_SZ * O_SZ) + n0;
    const int t = threadIdx.x;
    const int am = t >> 3, ac = (t & 7) << 2;
    const int bk = (t >> 5) << 2, bn = (t & 31) << 2;
    const int wv = t >> 6, lane = t & 63;
    const int wr = (wv >> 1) << 6, wc = (wv & 1) << 6;
    const int hi = lane >> 4, lr = lane & 15;
    f32x4 acc[4][4] = {};
    f32x4 ra[4], rb[4];
    auto load_tile = [&](int kb) {
        #pragma unroll
        for (int p = 0; p < 4; ++p)
            ra[p] = *reinterpret_cast<const f32x4*>(Ag + (size_t)(am + 32 * p) * I_SZ + kb + ac);
        #pragma unroll
        for (int r = 0; r < 4; ++r)
            rb[r] = *reinterpret_cast<const f32x4*>(Wg + (size_t)(kb + bk + r) * O_SZ + bn);
    };
    auto store_tile = [&](int buf) {
        #pragma unroll
        for (int p = 0; p < 4; ++p) {
            s16x4 h = { f2bf(ra[p][0]), f2bf(ra[p][1]), f2bf(ra[p][2]), f2bf(ra[p][3]) };
            *reinterpret_cast<s16x4*>(&As[buf][(am + 32 * p) * LDK + ac]) = h;
        }
        #pragma unroll
        for (int i = 0; i < 4; ++i) {
            s16x4 h = { f2bf(rb[0][i]), f2bf(rb[1][i]), f2bf(rb[2][i]), f2bf(rb[3][i]) };
            *reinterpret_cast<s16x4*>(&Bs[buf][(bn + i) * LDK + bk]) = h;
        }
    };
    load_tile(0);
    store_tile(0);
    __syncthreads();
    for (int kt = 0; kt < NKT; ++kt) {
        const int cur = kt & 1;
        if (kt + 1 < NKT) load_tile((kt + 1) * BK);
        s16x8 af[4], bfr[4];
        #pragma unroll
        for (int im = 0; im < 4; ++im) {
            const short* p = &As[cur][(wr + im * 16 + lr) * LDK + 4 * hi];
            s16x4 lo = *reinterpret_cast<const s16x4*>(p);
            s16x4 hh = *reinterpret_cast<const s16x4*>(p + 16);
            af[im] = __builtin_shufflevector(lo, hh, 0, 1, 2, 3, 4, 5, 6, 7);
        }
        #pragma unroll
        for (int in = 0; in < 4; ++in) {
            const short* p = &Bs[cur][(wc + in * 16 + lr) * LDK + 4 * hi];
            s16x4 lo = *reinterpret_cast<const s16x4*>(p);
            s16x4 hh = *reinterpret_cast<const s16x4*>(p + 16);
            bfr[in] = __builtin_shufflevector(lo, hh, 0, 1, 2, 3, 4, 5, 6, 7);
        }
        #pragma unroll
        for (int im = 0; im < 4; ++im)
            #pragma unroll
            for (int in = 0; in < 4; ++in)
                acc[im][in] = __builtin_amdgcn_mfma_f32_16x16x32_bf16(
                                  af[im], bfr[in], acc[im][in], 0, 0, 0);
        if (kt + 1 < NKT) store_tile(cur ^ 1);
        __syncthreads();
    }
    float bias[4];
    #pragma unroll
    for (int in = 0; in < 4; ++in)
        bias[in] = bw[dom * O_SZ + n0 + wc + in * 16 + lr];
    const size_t obase = ((size_t)bz * T_SZ + m0) * O_SZ + n0;
    #pragma unroll
    for (int im = 0; im < 4; ++im) {
        #pragma unroll
        for (int r = 0; r < 4; ++r) {
            const int row = wr + im * 16 + hi * 4 + r;
            float* orow = out + obase + (size_t)row * O_SZ;
            #pragma unroll
            for (int in = 0; in < 4; ++in)
                orow[wc + in * 16 + lr] = acc[im][in][r] + bias[in];
        }
    }
}

extern "C" void kernel_launch(void* const* d_in, const int* in_sizes, int n_in,
                              void* d_out, int out_size, void* d_ws, size_t ws_size,
                              hipStream_t stream) {
    const float* x   = (const float*)d_in[0];
    const int*   dom = (const int*)d_in[1];
    const float* fcw = (const float*)d_in[2];
    const float* bw  = (const float*)d_in[3];
    float* out = (float*)d_out;
    const int B = in_sizes[1];   // 16

    if (ws_size >= WS_NEEDED && B == B_MAX) {
        short* xt = (short*)d_ws;
        short* wt = xt + XT_ELEMS;
        const int chunks = B * 16 * 64 * 512;             // 8,388,608
        convA<<<chunks / 256, 256, 0, stream>>>(x, xt);
        convB<<<chunks / 256, 256, 0, stream>>>(fcw, dom, wt);
        gemm_bf16<<<dim3(16, 16, B), 256, 0, stream>>>(xt, wt, bw, dom, out);
    } else {
        dim3 grid(O_SZ / BN, T_SZ / BM, B);
        dal_gemm<<<grid, dim3(256), 0, stream>>>(x, dom, fcw, bw, out);
    }
}

// Round 4
// 532.403 us; speedup vs baseline: 1.2140x; 1.0931x over previous
//
#include <hip/hip_runtime.h>
#include <hip/hip_bf16.h>
#include <stdint.h>

typedef __attribute__((ext_vector_type(4))) float  f32x4;
typedef __attribute__((ext_vector_type(8))) short  s16x8;
typedef __attribute__((ext_vector_type(4))) short  s16x4;

constexpr int I_SZ = 2048;
constexpr int O_SZ = 2048;
constexpr int T_SZ = 2048;
constexpr int B_MAX = 16;

// pre-tiled layout: per (bz, mtile/ntile of 128, ktile of 32): 8KB block =
// 8 subtiles (16 rows each) x 1KB; within a subtile, byte offset l*16 holds
// fragment of lane l: row = l&15, k = 4*(l>>4) + {0..3} and 16 + 4*(l>>4) + {0..3}
constexpr size_t XT_ELEMS = (size_t)B_MAX * T_SZ * I_SZ;         // 67,108,864 shorts
constexpr size_t WT_ELEMS = (size_t)B_MAX * I_SZ * O_SZ;
constexpr size_t WS_NEEDED = (XT_ELEMS + WT_ELEMS) * sizeof(short); // 256 MB

__device__ __forceinline__ short f2bf(float f) {
    __hip_bfloat16 h = __float2bfloat16(f);
    return *reinterpret_cast<short*>(&h);
}

__device__ __forceinline__ void gload_lds16(const void* g, void* l) {
    __builtin_amdgcn_global_load_lds(
        (const __attribute__((address_space(1))) unsigned int*)g,
        (__attribute__((address_space(3))) unsigned int*)l, 16, 0, 0);
}

// ---------------- conversion: x fp32 [B][T][I] -> pre-tiled bf16 ----------------
__global__ __launch_bounds__(256) void convA(const float* __restrict__ x,
                                             short* __restrict__ xt) {
    const int c = blockIdx.x * 256 + threadIdx.x;    // 16B-chunk id
    const int l  = c & 63;
    const int mi = (c >> 6) & 7;
    const int kt = (c >> 9) & 63;
    const int rest = c >> 15;                        // (bz*16 + mt)
    const int mt = rest & 15, bz = rest >> 4;
    const int lr = l & 15, hi = l >> 4;
    const int m = mt * 128 + mi * 16 + lr;
    const float* src = x + ((size_t)(bz * T_SZ + m)) * I_SZ + kt * 32 + 4 * hi;
    f32x4 a = *reinterpret_cast<const f32x4*>(src);
    f32x4 b = *reinterpret_cast<const f32x4*>(src + 16);
    s16x8 h = { f2bf(a[0]), f2bf(a[1]), f2bf(a[2]), f2bf(a[3]),
                f2bf(b[0]), f2bf(b[1]), f2bf(b[2]), f2bf(b[3]) };
    *reinterpret_cast<s16x8*>(xt + (size_t)c * 8) = h;
}

// ------- conversion: W fp32 [dom][I][O] gathered+transposed -> pre-tiled bf16 ----
__global__ __launch_bounds__(256) void convB(const float* __restrict__ fcw,
                                             const int* __restrict__ dom_id,
                                             short* __restrict__ wt) {
    const int c = blockIdx.x * 256 + threadIdx.x;
    const int l  = c & 63;
    const int ni = (c >> 6) & 7;
    const int kt = (c >> 9) & 63;
    const int rest = c >> 15;                        // (bz*16 + nt)
    const int nt = rest & 15, bz = rest >> 4;
    const int lr = l & 15, hi = l >> 4;
    const int n = nt * 128 + ni * 16 + lr;
    const int dom = dom_id[bz];
    const float* src = fcw + (size_t)dom * ((size_t)I_SZ * O_SZ)
                           + (size_t)(kt * 32 + 4 * hi) * O_SZ + n;
    short h[8];
    #pragma unroll
    for (int j = 0; j < 4; ++j) {
        h[j]     = f2bf(src[(size_t)j * O_SZ]);
        h[4 + j] = f2bf(src[(size_t)(16 + j) * O_SZ]);
    }
    *reinterpret_cast<s16x8*>(wt + (size_t)c * 8) =
        *reinterpret_cast<s16x8*>(h);
}

// ------------- bf16 GEMM, 256x256 tile, 4-deep ring buffer, counted vmcnt -------
// 8 waves: wm = wv>>2 (M half), wn = wv&3 (N quarter). Per wave: 128x64 output,
// acc[8][4] fragments. Per K-step (32): stage 4 x 1KB chunks/wave (A 16KB + B
// 16KB block-wide), 12 lane-linear ds_read_b128, 32 MFMA. vmcnt never drains
// below 12 in the main loop (3 stages in flight). Raw s_barrier (NOT
// __syncthreads, which force-drains vmcnt(0)).
__global__ __launch_bounds__(512, 2) void gemm_bf16_256(
        const short* __restrict__ xt, const short* __restrict__ wt,
        const float* __restrict__ bw, const int* __restrict__ dom_id,
        float* __restrict__ out) {
    __shared__ short As[4][8192];   // 4 ring buffers x 16KB (2 m-subtiles x 8KB)
    __shared__ short Bs[4][8192];

    // bijective XCD swizzle: nwg = 1024 = 8 XCDs x 128
    const int bid = blockIdx.x;
    const int swz = (bid & 7) * 128 + (bid >> 3);
    const int bz = swz >> 6;
    const int mb = (swz >> 3) & 7;   // 256-row tile index
    const int nb = swz & 7;          // 256-col tile index

    const short* Abase = xt + (size_t)(bz * 16 + mb * 2) * 64 * 4096;
    const short* Bbase = wt + (size_t)(bz * 16 + nb * 2) * 64 * 4096;

    const int t = threadIdx.x;
    const int wv = t >> 6, l = t & 63;
    const int wm = wv >> 2, wn = wv & 3;
    const int lr = l & 15, hi = l >> 4;
    const int bni = wn >> 1, bsub = (wn & 1) * 4;   // B block / subtile base

    auto stage = [&](int buf, int kt) {
        #pragma unroll
        for (int i = 0; i < 2; ++i) {
            const int c = wv * 2 + i;              // 0..15
            const int mi = c >> 3, inner = c & 7;
            gload_lds16(Abase + (size_t)(mi * 64 + kt) * 4096 + inner * 512 + l * 8,
                        &As[buf][c * 512]);
        }
        #pragma unroll
        for (int i = 0; i < 2; ++i) {
            const int c = wv * 2 + i;
            const int ni = c >> 3, inner = c & 7;
            gload_lds16(Bbase + (size_t)(ni * 64 + kt) * 4096 + inner * 512 + l * 8,
                        &Bs[buf][c * 512]);
        }
    };

    f32x4 acc[8][4] = {};

    stage(0, 0); stage(1, 1); stage(2, 2);        // 12 loads in flight

    for (int kt = 0; kt < 64; ++kt) {
        const int cur = kt & 3;
        // barrier 1: all waves finished reading buf[(kt+3)&3] (last read at kt-1)
        asm volatile("s_barrier" ::: "memory");
        // stage ahead by 3; at the tail, dummy re-stage kt=63 into dead buffers
        // so the outstanding count stays uniform and vmcnt(12) below is exact.
        stage((kt + 3) & 3, (kt + 3 < 64) ? kt + 3 : 63);
        // drain the stage issued 3 iterations ago (FIFO: oldest 4 of 16) -> buf[cur] ready
        asm volatile("s_waitcnt vmcnt(12)" ::: "memory");
        // barrier 2: every wave's chunk of buf[cur] has landed
        asm volatile("s_barrier" ::: "memory");

        s16x8 bf[4], af[8];
        #pragma unroll
        for (int g = 0; g < 4; ++g)
            bf[g] = *reinterpret_cast<const s16x8*>(
                        &Bs[cur][bni * 4096 + (bsub + g) * 512 + l * 8]);
        #pragma unroll
        for (int f = 0; f < 8; ++f)
            af[f] = *reinterpret_cast<const s16x8*>(
                        &As[cur][wm * 4096 + f * 512 + l * 8]);

        __builtin_amdgcn_s_setprio(1);
        #pragma unroll
        for (int f = 0; f < 8; ++f)
            #pragma unroll
            for (int g = 0; g < 4; ++g)
                acc[f][g] = __builtin_amdgcn_mfma_f32_16x16x32_bf16(
                                af[f], bf[g], acc[f][g], 0, 0, 0);
        __builtin_amdgcn_s_setprio(0);
    }

    // epilogue: bias + store (wave tile: rows wm*128..+128, cols wn*64..+64)
    const int dom = dom_id[bz];
    const int col0 = nb * 256 + wn * 64;
    float bias[4];
    #pragma unroll
    for (int g = 0; g < 4; ++g)
        bias[g] = bw[dom * O_SZ + col0 + g * 16 + lr];

    const size_t obase = ((size_t)bz * T_SZ + mb * 256 + wm * 128) * O_SZ + col0;
    #pragma unroll
    for (int f = 0; f < 8; ++f) {
        #pragma unroll
        for (int r = 0; r < 4; ++r) {
            const int row = f * 16 + hi * 4 + r;
            float* orow = out + obase + (size_t)row * O_SZ;
            #pragma unroll
            for (int g = 0; g < 4; ++g)
                orow[g * 16 + lr] = acc[f][g][r] + bias[g];
        }
    }
}

// =============== fallback (round-1 kernel) if workspace is too small ===============
constexpr int BM = 128, BN = 128, BK = 32;
constexpr int LDK = 40;
constexpr int NKT = I_SZ / BK;

__global__ __launch_bounds__(256) void dal_gemm(
    const float* __restrict__ x, const int* __restrict__ dom_id,
    const float* __restrict__ fcw, const float* __restrict__ bw,
    float* __restrict__ out)
{
    __shared__ short As[2][BM * LDK];
    __shared__ short Bs[2][BN * LDK];
    const int bz = blockIdx.z;
    const int m0 = blockIdx.y * BM, n0 = blockIdx.x * BN;
    const int dom = dom_id[bz];
    const float* Ag = x + ((size_t)bz * T_SZ + m0) * I_SZ;
    const float* Wg = fcw + (size_t)dom * ((size_t)I_SZ * O_SZ) + n0;
    const int t = threadIdx.x;
    const int am = t >> 3, ac = (t & 7) << 2;
    const int bk = (t >> 5) << 2, bn = (t & 31) << 2;
    const int wv = t >> 6, lane = t & 63;
    const int wr = (wv >> 1) << 6, wc = (wv & 1) << 6;
    const int hi = lane >> 4, lr = lane & 15;
    f32x4 acc[4][4] = {};
    f32x4 ra[4], rb[4];
    auto load_tile = [&](int kb) {
        #pragma unroll
        for (int p = 0; p < 4; ++p)
            ra[p] = *reinterpret_cast<const f32x4*>(Ag + (size_t)(am + 32 * p) * I_SZ + kb + ac);
        #pragma unroll
        for (int r = 0; r < 4; ++r)
            rb[r] = *reinterpret_cast<const f32x4*>(Wg + (size_t)(kb + bk + r) * O_SZ + bn);
    };
    auto store_tile = [&](int buf) {
        #pragma unroll
        for (int p = 0; p < 4; ++p) {
            s16x4 h = { f2bf(ra[p][0]), f2bf(ra[p][1]), f2bf(ra[p][2]), f2bf(ra[p][3]) };
            *reinterpret_cast<s16x4*>(&As[buf][(am + 32 * p) * LDK + ac]) = h;
        }
        #pragma unroll
        for (int i = 0; i < 4; ++i) {
            s16x4 h = { f2bf(rb[0][i]), f2bf(rb[1][i]), f2bf(rb[2][i]), f2bf(rb[3][i]) };
            *reinterpret_cast<s16x4*>(&Bs[buf][(bn + i) * LDK + bk]) = h;
        }
    };
    load_tile(0);
    store_tile(0);
    __syncthreads();
    for (int kt = 0; kt < NKT; ++kt) {
        const int cur = kt & 1;
        if (kt + 1 < NKT) load_tile((kt + 1) * BK);
        s16x8 af[4], bfr[4];
        #pragma unroll
        for (int im = 0; im < 4; ++im) {
            const short* p = &As[cur][(wr + im * 16 + lr) * LDK + 4 * hi];
            s16x4 lo = *reinterpret_cast<const s16x4*>(p);
            s16x4 hh = *reinterpret_cast<const s16x4*>(p + 16);
            af[im] = __builtin_shufflevector(lo, hh, 0, 1, 2, 3, 4, 5, 6, 7);
        }
        #pragma unroll
        for (int in = 0; in < 4; ++in) {
            const short* p = &Bs[cur][(wc + in * 16 + lr) * LDK + 4 * hi];
            s16x4 lo = *reinterpret_cast<const s16x4*>(p);
            s16x4 hh = *reinterpret_cast<const s16x4*>(p + 16);
            bfr[in] = __builtin_shufflevector(lo, hh, 0, 1, 2, 3, 4, 5, 6, 7);
        }
        #pragma unroll
        for (int im = 0; im < 4; ++im)
            #pragma unroll
            for (int in = 0; in < 4; ++in)
                acc[im][in] = __builtin_amdgcn_mfma_f32_16x16x32_bf16(
                                  af[im], bfr[in], acc[im][in], 0, 0, 0);
        if (kt + 1 < NKT) store_tile(cur ^ 1);
        __syncthreads();
    }
    float bias[4];
    #pragma unroll
    for (int in = 0; in < 4; ++in)
        bias[in] = bw[dom * O_SZ + n0 + wc + in * 16 + lr];
    const size_t obase = ((size_t)bz * T_SZ + m0) * O_SZ + n0;
    #pragma unroll
    for (int im = 0; im < 4; ++im) {
        #pragma unroll
        for (int r = 0; r < 4; ++r) {
            const int row = wr + im * 16 + hi * 4 + r;
            float* orow = out + obase + (size_t)row * O_SZ;
            #pragma unroll
            for (int in = 0; in < 4; ++in)
                orow[wc + in * 16 + lr] = acc[im][in][r] + bias[in];
        }
    }
}

extern "C" void kernel_launch(void* const* d_in, const int* in_sizes, int n_in,
                              void* d_out, int out_size, void* d_ws, size_t ws_size,
                              hipStream_t stream) {
    const float* x   = (const float*)d_in[0];
    const int*   dom = (const int*)d_in[1];
    const float* fcw = (const float*)d_in[2];
    const float* bw  = (const float*)d_in[3];
    float* out = (float*)d_out;
    const int B = in_sizes[1];   // 16

    if (ws_size >= WS_NEEDED && B == B_MAX) {
        short* xt = (short*)d_ws;
        short* wt = xt + XT_ELEMS;
        const int chunks = B * 16 * 64 * 512;             // 8,388,608
        convA<<<chunks / 256, 256, 0, stream>>>(x, xt);
        convB<<<chunks / 256, 256, 0, stream>>>(fcw, dom, wt);
        gemm_bf16_256<<<dim3(1024), dim3(512), 0, stream>>>(xt, wt, bw, dom, out);
    } else {
        dim3 grid(O_SZ / BN, T_SZ / BM, B);
        dal_gemm<<<grid, dim3(256), 0, stream>>>(x, dom, fcw, bw, out);
    }
}

// Round 5
// 526.372 us; speedup vs baseline: 1.2280x; 1.0115x over previous
//
#include <hip/hip_runtime.h>
#include <hip/hip_bf16.h>
#include <stdint.h>

typedef __attribute__((ext_vector_type(4))) float  f32x4;
typedef __attribute__((ext_vector_type(8))) short  s16x8;
typedef __attribute__((ext_vector_type(4))) short  s16x4;

constexpr int I_SZ = 2048;
constexpr int O_SZ = 2048;
constexpr int T_SZ = 2048;
constexpr int B_MAX = 16;

// pre-tiled layout: per (bz, mtile/ntile of 128, ktile of 32): 8KB block =
// 8 subtiles (16 rows each) x 1KB; within a subtile, byte offset l*16 holds
// fragment of lane l: row = l&15, k = 4*(l>>4) + {0..3} and 16 + 4*(l>>4) + {0..3}
constexpr size_t XT_ELEMS = (size_t)B_MAX * T_SZ * I_SZ;         // 67,108,864 shorts
constexpr size_t WT_ELEMS = (size_t)B_MAX * I_SZ * O_SZ;
constexpr size_t WS_NEEDED = (XT_ELEMS + WT_ELEMS) * sizeof(short); // 256 MB

__device__ __forceinline__ short f2bf(float f) {
    __hip_bfloat16 h = __float2bfloat16(f);
    return *reinterpret_cast<short*>(&h);
}

__device__ __forceinline__ void gload_lds16(const void* g, void* l) {
    __builtin_amdgcn_global_load_lds(
        (const __attribute__((address_space(1))) unsigned int*)g,
        (__attribute__((address_space(3))) unsigned int*)l, 16, 0, 0);
}

// ---------------- conversion: x fp32 [B][T][I] -> pre-tiled bf16 ----------------
__global__ __launch_bounds__(256) void convA(const float* __restrict__ x,
                                             short* __restrict__ xt) {
    const int c = blockIdx.x * 256 + threadIdx.x;    // 16B-chunk id
    const int l  = c & 63;
    const int mi = (c >> 6) & 7;
    const int kt = (c >> 9) & 63;
    const int rest = c >> 15;                        // (bz*16 + mt)
    const int mt = rest & 15, bz = rest >> 4;
    const int lr = l & 15, hi = l >> 4;
    const int m = mt * 128 + mi * 16 + lr;
    const float* src = x + ((size_t)(bz * T_SZ + m)) * I_SZ + kt * 32 + 4 * hi;
    f32x4 a = *reinterpret_cast<const f32x4*>(src);
    f32x4 b = *reinterpret_cast<const f32x4*>(src + 16);
    s16x8 h = { f2bf(a[0]), f2bf(a[1]), f2bf(a[2]), f2bf(a[3]),
                f2bf(b[0]), f2bf(b[1]), f2bf(b[2]), f2bf(b[3]) };
    *reinterpret_cast<s16x8*>(xt + (size_t)c * 8) = h;
}

// ------- conversion: W fp32 [dom][I][O] gathered+transposed -> pre-tiled bf16 ----
__global__ __launch_bounds__(256) void convB(const float* __restrict__ fcw,
                                             const int* __restrict__ dom_id,
                                             short* __restrict__ wt) {
    const int c = blockIdx.x * 256 + threadIdx.x;
    const int l  = c & 63;
    const int ni = (c >> 6) & 7;
    const int kt = (c >> 9) & 63;
    const int rest = c >> 15;                        // (bz*16 + nt)
    const int nt = rest & 15, bz = rest >> 4;
    const int lr = l & 15, hi = l >> 4;
    const int n = nt * 128 + ni * 16 + lr;
    const int dom = dom_id[bz];
    const float* src = fcw + (size_t)dom * ((size_t)I_SZ * O_SZ)
                           + (size_t)(kt * 32 + 4 * hi) * O_SZ + n;
    short h[8];
    #pragma unroll
    for (int j = 0; j < 4; ++j) {
        h[j]     = f2bf(src[(size_t)j * O_SZ]);
        h[4 + j] = f2bf(src[(size_t)(16 + j) * O_SZ]);
    }
    *reinterpret_cast<s16x8*>(wt + (size_t)c * 8) =
        *reinterpret_cast<s16x8*>(h);
}

// ------------- bf16 GEMM, 256x256 tile, 4-deep ring, counted vmcnt, read-ahead --
// 8 waves: wm = wv>>2 (M half), wn = wv&3 (N quarter). Per wave: 128x64 output.
// Per K-step: [bar1][stage kt+3][vmcnt(8)][bar2][ds_read frags for kt+1 into the
// ALTERNATE reg set][32 MFMA on current reg set]. vmcnt(8) + bar2 guarantees ALL
// waves' stages for kt AND kt+1 have landed, so the read-ahead is race-free.
// LDS-read latency/pipe time overlaps the MFMA pipe within each wave.
__global__ __launch_bounds__(512, 2) void gemm_bf16_256(
        const short* __restrict__ xt, const short* __restrict__ wt,
        const float* __restrict__ bw, const int* __restrict__ dom_id,
        float* __restrict__ out) {
    __shared__ short As[4][8192];   // 4 ring buffers x 16KB (2 m-subtiles x 8KB)
    __shared__ short Bs[4][8192];

    // bijective XCD swizzle: nwg = 1024 = 8 XCDs x 128
    const int bid = blockIdx.x;
    const int swz = (bid & 7) * 128 + (bid >> 3);
    const int bz = swz >> 6;
    const int mb = (swz >> 3) & 7;   // 256-row tile index
    const int nb = swz & 7;          // 256-col tile index

    const short* Abase = xt + (size_t)(bz * 16 + mb * 2) * 64 * 4096;
    const short* Bbase = wt + (size_t)(bz * 16 + nb * 2) * 64 * 4096;

    const int t = threadIdx.x;
    const int wv = t >> 6, l = t & 63;
    const int wm = wv >> 2, wn = wv & 3;
    const int lr = l & 15, hi = l >> 4;
    const int bni = wn >> 1, bsub = (wn & 1) * 4;   // B block / subtile base

    auto stage = [&](int buf, int kt) {
        #pragma unroll
        for (int i = 0; i < 2; ++i) {
            const int c = wv * 2 + i;              // 0..15
            const int mi = c >> 3, inner = c & 7;
            gload_lds16(Abase + (size_t)(mi * 64 + kt) * 4096 + inner * 512 + l * 8,
                        &As[buf][c * 512]);
        }
        #pragma unroll
        for (int i = 0; i < 2; ++i) {
            const int c = wv * 2 + i;
            const int ni = c >> 3, inner = c & 7;
            gload_lds16(Bbase + (size_t)(ni * 64 + kt) * 4096 + inner * 512 + l * 8,
                        &Bs[buf][c * 512]);
        }
    };

    f32x4 acc[8][4] = {};
    s16x8 afA[8], bfA[4], afB[8], bfB[4];   // double-buffered fragment regs

    auto read_frags = [&](int buf, s16x8* af, s16x8* bf) {
        #pragma unroll
        for (int g = 0; g < 4; ++g)
            bf[g] = *reinterpret_cast<const s16x8*>(
                        &Bs[buf][bni * 4096 + (bsub + g) * 512 + l * 8]);
        #pragma unroll
        for (int f = 0; f < 8; ++f)
            af[f] = *reinterpret_cast<const s16x8*>(
                        &As[buf][wm * 4096 + f * 512 + l * 8]);
    };

    auto mfma32 = [&](const s16x8* af, const s16x8* bf) {
        __builtin_amdgcn_s_setprio(1);
        #pragma unroll
        for (int f = 0; f < 8; ++f)
            #pragma unroll
            for (int g = 0; g < 4; ++g)
                acc[f][g] = __builtin_amdgcn_mfma_f32_16x16x32_bf16(
                                af[f], bf[g], acc[f][g], 0, 0, 0);
        __builtin_amdgcn_s_setprio(0);
    };

    // prologue: 12 loads in flight; buf0 globally complete after vmcnt(8)+barrier
    stage(0, 0); stage(1, 1); stage(2, 2);
    asm volatile("s_waitcnt vmcnt(8)" ::: "memory");
    asm volatile("s_barrier" ::: "memory");
    read_frags(0, afA, bfA);

    // hand-unrolled x2 so the A/B register sets are statically indexed (rule 20)
    for (int kt = 0; kt < 64; kt += 2) {
        // ---- even step: compute kt (regs A), read-ahead kt+1 (regs B) ----
        asm volatile("s_barrier" ::: "memory");                 // readers of buf[(kt+3)&3] done
        stage((kt + 3) & 3, (kt + 3 > 63) ? 63 : kt + 3);       // dummy re-stage at tail keeps vmcnt exact
        asm volatile("s_waitcnt vmcnt(8)" ::: "memory");        // own stages kt, kt+1 landed
        asm volatile("s_barrier" ::: "memory");                 // ALL waves' stages kt, kt+1 landed
        read_frags((kt + 1) & 3, afB, bfB);
        mfma32(afA, bfA);

        // ---- odd step: compute kt+1 (regs B), read-ahead kt+2 (regs A) ----
        asm volatile("s_barrier" ::: "memory");
        stage((kt + 4) & 3, (kt + 4 > 63) ? 63 : kt + 4);
        asm volatile("s_waitcnt vmcnt(8)" ::: "memory");
        asm volatile("s_barrier" ::: "memory");
        read_frags((kt + 2) & 3, afA, bfA);                     // at kt=62 this reads a dead
        mfma32(afB, bfB);                                       // dummy buffer; regs unused
    }

    // epilogue: bias + store (wave tile: rows wm*128..+128, cols wn*64..+64)
    const int dom = dom_id[bz];
    const int col0 = nb * 256 + wn * 64;
    float bias[4];
    #pragma unroll
    for (int g = 0; g < 4; ++g)
        bias[g] = bw[dom * O_SZ + col0 + g * 16 + lr];

    const size_t obase = ((size_t)bz * T_SZ + mb * 256 + wm * 128) * O_SZ + col0;
    #pragma unroll
    for (int f = 0; f < 8; ++f) {
        #pragma unroll
        for (int r = 0; r < 4; ++r) {
            const int row = f * 16 + hi * 4 + r;
            float* orow = out + obase + (size_t)row * O_SZ;
            #pragma unroll
            for (int g = 0; g < 4; ++g)
                orow[g * 16 + lr] = acc[f][g][r] + bias[g];
        }
    }
}

// =============== fallback (round-1 kernel) if workspace is too small ===============
constexpr int BM = 128, BN = 128, BK = 32;
constexpr int LDK = 40;
constexpr int NKT = I_SZ / BK;

__global__ __launch_bounds__(256) void dal_gemm(
    const float* __restrict__ x, const int* __restrict__ dom_id,
    const float* __restrict__ fcw, const float* __restrict__ bw,
    float* __restrict__ out)
{
    __shared__ short As[2][BM * LDK];
    __shared__ short Bs[2][BN * LDK];
    const int bz = blockIdx.z;
    const int m0 = blockIdx.y * BM, n0 = blockIdx.x * BN;
    const int dom = dom_id[bz];
    const float* Ag = x + ((size_t)bz * T_SZ + m0) * I_SZ;
    const float* Wg = fcw + (size_t)dom * ((size_t)I_SZ * O_SZ) + n0;
    const int t = threadIdx.x;
    const int am = t >> 3, ac = (t & 7) << 2;
    const int bk = (t >> 5) << 2, bn = (t & 31) << 2;
    const int wv = t >> 6, lane = t & 63;
    const int wr = (wv >> 1) << 6, wc = (wv & 1) << 6;
    const int hi = lane >> 4, lr = lane & 15;
    f32x4 acc[4][4] = {};
    f32x4 ra[4], rb[4];
    auto load_tile = [&](int kb) {
        #pragma unroll
        for (int p = 0; p < 4; ++p)
            ra[p] = *reinterpret_cast<const f32x4*>(Ag + (size_t)(am + 32 * p) * I_SZ + kb + ac);
        #pragma unroll
        for (int r = 0; r < 4; ++r)
            rb[r] = *reinterpret_cast<const f32x4*>(Wg + (size_t)(kb + bk + r) * O_SZ + bn);
    };
    auto store_tile = [&](int buf) {
        #pragma unroll
        for (int p = 0; p < 4; ++p) {
            s16x4 h = { f2bf(ra[p][0]), f2bf(ra[p][1]), f2bf(ra[p][2]), f2bf(ra[p][3]) };
            *reinterpret_cast<s16x4*>(&As[buf][(am + 32 * p) * LDK + ac]) = h;
        }
        #pragma unroll
        for (int i = 0; i < 4; ++i) {
            s16x4 h = { f2bf(rb[0][i]), f2bf(rb[1][i]), f2bf(rb[2][i]), f2bf(rb[3][i]) };
            *reinterpret_cast<s16x4*>(&Bs[buf][(bn + i) * LDK + bk]) = h;
        }
    };
    load_tile(0);
    store_tile(0);
    __syncthreads();
    for (int kt = 0; kt < NKT; ++kt) {
        const int cur = kt & 1;
        if (kt + 1 < NKT) load_tile((kt + 1) * BK);
        s16x8 af[4], bfr[4];
        #pragma unroll
        for (int im = 0; im < 4; ++im) {
            const short* p = &As[cur][(wr + im * 16 + lr) * LDK + 4 * hi];
            s16x4 lo = *reinterpret_cast<const s16x4*>(p);
            s16x4 hh = *reinterpret_cast<const s16x4*>(p + 16);
            af[im] = __builtin_shufflevector(lo, hh, 0, 1, 2, 3, 4, 5, 6, 7);
        }
        #pragma unroll
        for (int in = 0; in < 4; ++in) {
            const short* p = &Bs[cur][(wc + in * 16 + lr) * LDK + 4 * hi];
            s16x4 lo = *reinterpret_cast<const s16x4*>(p);
            s16x4 hh = *reinterpret_cast<const s16x4*>(p + 16);
            bfr[in] = __builtin_shufflevector(lo, hh, 0, 1, 2, 3, 4, 5, 6, 7);
        }
        #pragma unroll
        for (int im = 0; im < 4; ++im)
            #pragma unroll
            for (int in = 0; in < 4; ++in)
                acc[im][in] = __builtin_amdgcn_mfma_f32_16x16x32_bf16(
                                  af[im], bfr[in], acc[im][in], 0, 0, 0);
        if (kt + 1 < NKT) store_tile(cur ^ 1);
        __syncthreads();
    }
    float bias[4];
    #pragma unroll
    for (int in = 0; in < 4; ++in)
        bias[in] = bw[dom * O_SZ + n0 + wc + in * 16 + lr];
    const size_t obase = ((size_t)bz * T_SZ + m0) * O_SZ + n0;
    #pragma unroll
    for (int im = 0; im < 4; ++im) {
        #pragma unroll
        for (int r = 0; r < 4; ++r) {
            const int row = wr + im * 16 + hi * 4 + r;
            float* orow = out + obase + (size_t)row * O_SZ;
            #pragma unroll
            for (int in = 0; in < 4; ++in)
                orow[wc + in * 16 + lr] = acc[im][in][r] + bias[in];
        }
    }
}

extern "C" void kernel_launch(void* const* d_in, const int* in_sizes, int n_in,
                              void* d_out, int out_size, void* d_ws, size_t ws_size,
                              hipStream_t stream) {
    const float* x   = (const float*)d_in[0];
    const int*   dom = (const int*)d_in[1];
    const float* fcw = (const float*)d_in[2];
    const float* bw  = (const float*)d_in[3];
    float* out = (float*)d_out;
    const int B = in_sizes[1];   // 16

    if (ws_size >= WS_NEEDED && B == B_MAX) {
        short* xt = (short*)d_ws;
        short* wt = xt + XT_ELEMS;
        const int chunks = B * 16 * 64 * 512;             // 8,388,608
        convA<<<chunks / 256, 256, 0, stream>>>(x, xt);
        convB<<<chunks / 256, 256, 0, stream>>>(fcw, dom, wt);
        gemm_bf16_256<<<dim3(1024), dim3(512), 0, stream>>>(xt, wt, bw, dom, out);
    } else {
        dim3 grid(O_SZ / BN, T_SZ / BM, B);
        dal_gemm<<<grid, dim3(256), 0, stream>>>(x, dom, fcw, bw, out);
    }
}

// Round 6
// 506.888 us; speedup vs baseline: 1.2752x; 1.0384x over previous
//
#include <hip/hip_runtime.h>
#include <hip/hip_bf16.h>
#include <stdint.h>

typedef __attribute__((ext_vector_type(4))) float  f32x4;
typedef __attribute__((ext_vector_type(8))) short  s16x8;
typedef __attribute__((ext_vector_type(4))) short  s16x4;

constexpr int I_SZ = 2048;
constexpr int O_SZ = 2048;
constexpr int T_SZ = 2048;
constexpr int B_MAX = 16;

// pre-tiled layout: per (bz, mtile/ntile of 128, ktile of 32): 8KB block =
// 8 subtiles (16 rows each) x 1KB; within a subtile, byte offset l*16 holds
// fragment of lane l: row = l&15, k = 4*(l>>4) + {0..3} and 16 + 4*(l>>4) + {0..3}
constexpr size_t XT_ELEMS = (size_t)B_MAX * T_SZ * I_SZ;         // 67,108,864 shorts
constexpr size_t WT_ELEMS = (size_t)B_MAX * I_SZ * O_SZ;
constexpr size_t WS_NEEDED = (XT_ELEMS + WT_ELEMS) * sizeof(short); // 256 MB

__device__ __forceinline__ short f2bf(float f) {
    __hip_bfloat16 h = __float2bfloat16(f);
    return *reinterpret_cast<short*>(&h);
}

__device__ __forceinline__ void gload_lds16(const void* g, void* l) {
    __builtin_amdgcn_global_load_lds(
        (const __attribute__((address_space(1))) unsigned int*)g,
        (__attribute__((address_space(3))) unsigned int*)l, 16, 0, 0);
}

// ---------------- conversion: x fp32 [B][T][I] -> pre-tiled bf16 ----------------
__global__ __launch_bounds__(256) void convA(const float* __restrict__ x,
                                             short* __restrict__ xt) {
    const int c = blockIdx.x * 256 + threadIdx.x;    // 16B-chunk id
    const int l  = c & 63;
    const int mi = (c >> 6) & 7;
    const int kt = (c >> 9) & 63;
    const int rest = c >> 15;                        // (bz*16 + mt)
    const int mt = rest & 15, bz = rest >> 4;
    const int lr = l & 15, hi = l >> 4;
    const int m = mt * 128 + mi * 16 + lr;
    const float* src = x + ((size_t)(bz * T_SZ + m)) * I_SZ + kt * 32 + 4 * hi;
    f32x4 a = *reinterpret_cast<const f32x4*>(src);
    f32x4 b = *reinterpret_cast<const f32x4*>(src + 16);
    s16x8 h = { f2bf(a[0]), f2bf(a[1]), f2bf(a[2]), f2bf(a[3]),
                f2bf(b[0]), f2bf(b[1]), f2bf(b[2]), f2bf(b[3]) };
    *reinterpret_cast<s16x8*>(xt + (size_t)c * 8) = h;
}

// ------- conversion: W fp32 [dom][I][O] gathered+transposed -> pre-tiled bf16 ----
__global__ __launch_bounds__(256) void convB(const float* __restrict__ fcw,
                                             const int* __restrict__ dom_id,
                                             short* __restrict__ wt) {
    const int c = blockIdx.x * 256 + threadIdx.x;
    const int l  = c & 63;
    const int ni = (c >> 6) & 7;
    const int kt = (c >> 9) & 63;
    const int rest = c >> 15;                        // (bz*16 + nt)
    const int nt = rest & 15, bz = rest >> 4;
    const int lr = l & 15, hi = l >> 4;
    const int n = nt * 128 + ni * 16 + lr;
    const int dom = dom_id[bz];
    const float* src = fcw + (size_t)dom * ((size_t)I_SZ * O_SZ)
                           + (size_t)(kt * 32 + 4 * hi) * O_SZ + n;
    short h[8];
    #pragma unroll
    for (int j = 0; j < 4; ++j) {
        h[j]     = f2bf(src[(size_t)j * O_SZ]);
        h[4 + j] = f2bf(src[(size_t)(16 + j) * O_SZ]);
    }
    *reinterpret_cast<s16x8*>(wt + (size_t)c * 8) =
        *reinterpret_cast<s16x8*>(h);
}

// ------------- bf16 GEMM, 256x256 tile, ring-4, counted vmcnt, 2-phase K-step ---
// 8 waves: wm = wv>>2 (M half), wn = wv&3 (N quarter). Per wave: 128x64 output.
// Per K-step (m201-style): vmcnt(8); BAR; {read A0-3,B0-3 || stage A-chunks kt+3};
// BAR; 16 MFMA; {read A4-7 || stage B-chunks kt+3}; BAR; 16 MFMA.
// vmcnt never drains below 8 in the main loop; ds_reads and stage issue inside
// the compute phases so their latency rides under MFMA / barrier-wait time.
__global__ __launch_bounds__(512, 2) void gemm_bf16_256(
        const short* __restrict__ xt, const short* __restrict__ wt,
        const float* __restrict__ bw, const int* __restrict__ dom_id,
        float* __restrict__ out) {
    __shared__ short As[4][8192];   // 4 ring buffers x 16KB (2 m-subtiles x 8KB)
    __shared__ short Bs[4][8192];

    // bijective XCD swizzle: nwg = 1024 = 8 XCDs x 128
    const int bid = blockIdx.x;
    const int swz = (bid & 7) * 128 + (bid >> 3);
    const int bz = swz >> 6;
    const int mb = (swz >> 3) & 7;   // 256-row tile index
    const int nb = swz & 7;          // 256-col tile index

    const short* Abase = xt + (size_t)(bz * 16 + mb * 2) * 64 * 4096;
    const short* Bbase = wt + (size_t)(bz * 16 + nb * 2) * 64 * 4096;

    const int t = threadIdx.x;
    const int wv = t >> 6, l = t & 63;
    const int wm = wv >> 2, wn = wv & 3;
    const int lr = l & 15, hi = l >> 4;
    const int bni = wn >> 1, bsub = (wn & 1) * 4;   // B block / subtile base

    auto stageA = [&](int buf, int kt) {
        #pragma unroll
        for (int i = 0; i < 2; ++i) {
            const int c = wv * 2 + i;              // 0..15
            const int mi = c >> 3, inner = c & 7;
            gload_lds16(Abase + (size_t)(mi * 64 + kt) * 4096 + inner * 512 + l * 8,
                        &As[buf][c * 512]);
        }
    };
    auto stageB = [&](int buf, int kt) {
        #pragma unroll
        for (int i = 0; i < 2; ++i) {
            const int c = wv * 2 + i;
            const int ni = c >> 3, inner = c & 7;
            gload_lds16(Bbase + (size_t)(ni * 64 + kt) * 4096 + inner * 512 + l * 8,
                        &Bs[buf][c * 512]);
        }
    };

    f32x4 acc[8][4] = {};

    // prologue: 12 loads/wave in flight (steps 0,1,2), FIFO order A,B per step
    stageA(0, 0); stageB(0, 0);
    stageA(1, 1); stageB(1, 1);
    stageA(2, 2); stageB(2, 2);

    for (int kt = 0; kt < 64; ++kt) {
        const int cur = kt & 3;
        const int pre = (kt + 3) & 3;                 // stage target buffer
        const int pkt = (kt + 3 > 63) ? 63 : kt + 3;  // dummy re-stage at tail

        // own stage(kt) landed (4 oldest of 12 drained, 8 stay in flight)
        asm volatile("s_waitcnt vmcnt(8)" ::: "memory");
        asm volatile("s_barrier" ::: "memory");        // BAR-a: buf[cur] globally ready

        // ---- phase A: reads + A-staging, then first MFMA quadrant ----
        s16x8 af[4], bq[4];
        #pragma unroll
        for (int g = 0; g < 4; ++g)
            bq[g] = *reinterpret_cast<const s16x8*>(
                        &Bs[cur][bni * 4096 + (bsub + g) * 512 + l * 8]);
        #pragma unroll
        for (int f = 0; f < 4; ++f)
            af[f] = *reinterpret_cast<const s16x8*>(
                        &As[cur][wm * 4096 + f * 512 + l * 8]);
        stageA(pre, pkt);
        asm volatile("s_barrier" ::: "memory");        // BAR-b

        __builtin_amdgcn_s_setprio(1);
        #pragma unroll
        for (int f = 0; f < 4; ++f)
            #pragma unroll
            for (int g = 0; g < 4; ++g)
                acc[f][g] = __builtin_amdgcn_mfma_f32_16x16x32_bf16(
                                af[f], bq[g], acc[f][g], 0, 0, 0);
        __builtin_amdgcn_s_setprio(0);

        // ---- phase B: reads + B-staging, then second MFMA quadrant ----
        s16x8 af2[4];
        #pragma unroll
        for (int f = 0; f < 4; ++f)
            af2[f] = *reinterpret_cast<const s16x8*>(
                        &As[cur][wm * 4096 + (4 + f) * 512 + l * 8]);
        stageB(pre, pkt);
        asm volatile("s_barrier" ::: "memory");        // BAR-c

        __builtin_amdgcn_s_setprio(1);
        #pragma unroll
        for (int f = 0; f < 4; ++f)
            #pragma unroll
            for (int g = 0; g < 4; ++g)
                acc[4 + f][g] = __builtin_amdgcn_mfma_f32_16x16x32_bf16(
                                    af2[f], bq[g], acc[4 + f][g], 0, 0, 0);
        __builtin_amdgcn_s_setprio(0);
    }

    // retire the tail's outstanding dummy stages before epilogue/endpgm
    asm volatile("s_waitcnt vmcnt(0)" ::: "memory");

    // epilogue: bias + store (wave tile: rows wm*128..+128, cols wn*64..+64)
    const int dom = dom_id[bz];
    const int col0 = nb * 256 + wn * 64;
    float bias[4];
    #pragma unroll
    for (int g = 0; g < 4; ++g)
        bias[g] = bw[dom * O_SZ + col0 + g * 16 + lr];

    const size_t obase = ((size_t)bz * T_SZ + mb * 256 + wm * 128) * O_SZ + col0;
    #pragma unroll
    for (int f = 0; f < 8; ++f) {
        #pragma unroll
        for (int r = 0; r < 4; ++r) {
            const int row = f * 16 + hi * 4 + r;
            float* orow = out + obase + (size_t)row * O_SZ;
            #pragma unroll
            for (int g = 0; g < 4; ++g)
                orow[g * 16 + lr] = acc[f][g][r] + bias[g];
        }
    }
}

// =============== fallback (round-1 kernel) if workspace is too small ===============
constexpr int BM = 128, BN = 128, BK = 32;
constexpr int LDK = 40;
constexpr int NKT = I_SZ / BK;

__global__ __launch_bounds__(256) void dal_gemm(
    const float* __restrict__ x, const int* __restrict__ dom_id,
    const float* __restrict__ fcw, const float* __restrict__ bw,
    float* __restrict__ out)
{
    __shared__ short As[2][BM * LDK];
    __shared__ short Bs[2][BN * LDK];
    const int bz = blockIdx.z;
    const int m0 = blockIdx.y * BM, n0 = blockIdx.x * BN;
    const int dom = dom_id[bz];
    const float* Ag = x + ((size_t)bz * T_SZ + m0) * I_SZ;
    const float* Wg = fcw + (size_t)dom * ((size_t)I_SZ * O_SZ) + n0;
    const int t = threadIdx.x;
    const int am = t >> 3, ac = (t & 7) << 2;
    const int bk = (t >> 5) << 2, bn = (t & 31) << 2;
    const int wv = t >> 6, lane = t & 63;
    const int wr = (wv >> 1) << 6, wc = (wv & 1) << 6;
    const int hi = lane >> 4, lr = lane & 15;
    f32x4 acc[4][4] = {};
    f32x4 ra[4], rb[4];
    auto load_tile = [&](int kb) {
        #pragma unroll
        for (int p = 0; p < 4; ++p)
            ra[p] = *reinterpret_cast<const f32x4*>(Ag + (size_t)(am + 32 * p) * I_SZ + kb + ac);
        #pragma unroll
        for (int r = 0; r < 4; ++r)
            rb[r] = *reinterpret_cast<const f32x4*>(Wg + (size_t)(kb + bk + r) * O_SZ + bn);
    };
    auto store_tile = [&](int buf) {
        #pragma unroll
        for (int p = 0; p < 4; ++p) {
            s16x4 h = { f2bf(ra[p][0]), f2bf(ra[p][1]), f2bf(ra[p][2]), f2bf(ra[p][3]) };
            *reinterpret_cast<s16x4*>(&As[buf][(am + 32 * p) * LDK + ac]) = h;
        }
        #pragma unroll
        for (int i = 0; i < 4; ++i) {
            s16x4 h = { f2bf(rb[0][i]), f2bf(rb[1][i]), f2bf(rb[2][i]), f2bf(rb[3][i]) };
            *reinterpret_cast<s16x4*>(&Bs[buf][(bn + i) * LDK + bk]) = h;
        }
    };
    load_tile(0);
    store_tile(0);
    __syncthreads();
    for (int kt = 0; kt < NKT; ++kt) {
        const int cur = kt & 1;
        if (kt + 1 < NKT) load_tile((kt + 1) * BK);
        s16x8 af[4], bfr[4];
        #pragma unroll
        for (int im = 0; im < 4; ++im) {
            const short* p = &As[cur][(wr + im * 16 + lr) * LDK + 4 * hi];
            s16x4 lo = *reinterpret_cast<const s16x4*>(p);
            s16x4 hh = *reinterpret_cast<const s16x4*>(p + 16);
            af[im] = __builtin_shufflevector(lo, hh, 0, 1, 2, 3, 4, 5, 6, 7);
        }
        #pragma unroll
        for (int in = 0; in < 4; ++in) {
            const short* p = &Bs[cur][(wc + in * 16 + lr) * LDK + 4 * hi];
            s16x4 lo = *reinterpret_cast<const s16x4*>(p);
            s16x4 hh = *reinterpret_cast<const s16x4*>(p + 16);
            bfr[in] = __builtin_shufflevector(lo, hh, 0, 1, 2, 3, 4, 5, 6, 7);
        }
        #pragma unroll
        for (int im = 0; im < 4; ++im)
            #pragma unroll
            for (int in = 0; in < 4; ++in)
                acc[im][in] = __builtin_amdgcn_mfma_f32_16x16x32_bf16(
                                  af[im], bfr[in], acc[im][in], 0, 0, 0);
        if (kt + 1 < NKT) store_tile(cur ^ 1);
        __syncthreads();
    }
    float bias[4];
    #pragma unroll
    for (int in = 0; in < 4; ++in)
        bias[in] = bw[dom * O_SZ + n0 + wc + in * 16 + lr];
    const size_t obase = ((size_t)bz * T_SZ + m0) * O_SZ + n0;
    #pragma unroll
    for (int im = 0; im < 4; ++im) {
        #pragma unroll
        for (int r = 0; r < 4; ++r) {
            const int row = wr + im * 16 + hi * 4 + r;
            float* orow = out + obase + (size_t)row * O_SZ;
            #pragma unroll
            for (int in = 0; in < 4; ++in)
                orow[wc + in * 16 + lr] = acc[im][in][r] + bias[in];
        }
    }
}

extern "C" void kernel_launch(void* const* d_in, const int* in_sizes, int n_in,
                              void* d_out, int out_size, void* d_ws, size_t ws_size,
                              hipStream_t stream) {
    const float* x   = (const float*)d_in[0];
    const int*   dom = (const int*)d_in[1];
    const float* fcw = (const float*)d_in[2];
    const float* bw  = (const float*)d_in[3];
    float* out = (float*)d_out;
    const int B = in_sizes[1];   // 16

    if (ws_size >= WS_NEEDED && B == B_MAX) {
        short* xt = (short*)d_ws;
        short* wt = xt + XT_ELEMS;
        const int chunks = B * 16 * 64 * 512;             // 8,388,608
        convA<<<chunks / 256, 256, 0, stream>>>(x, xt);
        convB<<<chunks / 256, 256, 0, stream>>>(fcw, dom, wt);
        gemm_bf16_256<<<dim3(1024), dim3(512), 0, stream>>>(xt, wt, bw, dom, out);
    } else {
        dim3 grid(O_SZ / BN, T_SZ / BM, B);
        dal_gemm<<<grid, dim3(256), 0, stream>>>(x, dom, fcw, bw, out);
    }
}